// Round 10
// baseline (405.706 us; speedup 1.0000x reference)
//
#include <hip/hip_runtime.h>
#include <math.h>

#define BATCH 32768
#define NSP 26
#define NDN 13
#define VOC 10000
#define EDIM 64
#define NLAY 3
#define HID1 256
#define HID2 128
#define XW 39             // NSP + NDN

typedef __fp16   fp16x2 __attribute__((ext_vector_type(2)));
typedef _Float16 half8  __attribute__((ext_vector_type(8)));
typedef float float4v   __attribute__((ext_vector_type(4)));

// ---- fp16 converts: all single-instruction on gfx950 ----
__device__ __forceinline__ unsigned pkh(float lo, float hi) {   // v_cvt_pkrtz_f16_f32
    fp16x2 h = __builtin_amdgcn_cvt_pkrtz(lo, hi);
    return __builtin_bit_cast(unsigned, h);
}
__device__ __forceinline__ unsigned short f2h(float f) {        // v_cvt_f16_f32 (RNE)
    return __builtin_bit_cast(unsigned short, (_Float16)f);
}
__device__ __forceinline__ float h2f(unsigned short h) {        // v_cvt_f32_f16
    return (float)__builtin_bit_cast(_Float16, h);
}
// pack a C-tile (4 f32 regs = rows quad*4+0..3, col c16) into 2 u32 fp16
__device__ __forceinline__ uint2 pkC(float4v c) {
    uint2 r; r.x = pkh(c[0], c[1]); r.y = pkh(c[2], c[3]); return r;
}
__device__ __forceinline__ void st4(unsigned short* p, float4v v) {
    *(uint2*)p = pkC(v);
}
// concat two packed C-tiles into one K=32 MFMA operand.  EXACT k-permutation
// trick: slots j=0..3 carry tile a (k=quad*4+j), slots 4..7 tile b
// (k=16+quad*4+(j-4)); same slot->k map for BOTH operands => dot unchanged.
__device__ __forceinline__ half8 cat(uint2 a, uint2 b) {
    union { unsigned u[4]; half8 h; } r;
    r.u[0] = a.x; r.u[1] = a.y; r.u[2] = b.x; r.u[3] = b.y;
    return r.h;
}
__device__ __forceinline__ half8 h8(uint4 u) {
    union { uint4 u; half8 h; } r; r.u = u; return r.h;
}

// ---------------------------------------------------------------------------
// K0: pack all weights into MFMA fragment order (fp16).
//  bid <  192 : Wq/Wk/Wv/Wres -> pW  [l][m][nt4][kt2][lane][j8]
//  192..1919  : W1 -> pW1 [c27][kt2][nt16][lane][j8], feature-chunk row order:
//               chunk c<26 covers W1 rows 13+c*64.. (emb feature c); chunk 26:
//               rows 0..12 (dense) then zero pad
//  1920..2047 : W2 -> pW2 [kc8][nt8][lane][j8]
// ---------------------------------------------------------------------------
__global__ void k_pack(const float* __restrict__ Wq, const float* __restrict__ Wk,
                       const float* __restrict__ Wv, const float* __restrict__ Wr,
                       const float* __restrict__ W1, const float* __restrict__ W2,
                       unsigned short* __restrict__ pW,
                       unsigned short* __restrict__ pW1,
                       unsigned short* __restrict__ pW2) {
    int bid = blockIdx.x;
    if (bid < 192) {
        int tid = bid * 256 + threadIdx.x;   // 49152 total
        int j    = tid & 7;
        int lane = (tid >> 3) & 63;
        int kt   = (tid >> 9) & 1;
        int nt   = (tid >> 10) & 3;
        int m    = (tid >> 12) & 3;
        int l    = tid >> 14;
        const float* W = (m == 0) ? Wq : (m == 1) ? Wk : (m == 2) ? Wv : Wr;
        int k = kt * 32 + ((lane >> 4) << 3) + j;
        int n = nt * 16 + (lane & 15);
        pW[tid] = f2h(W[l * EDIM * EDIM + k * EDIM + n]);
    } else if (bid < 1920) {
        int tid = (bid - 192) * 256 + threadIdx.x;   // 442368 total
        int j    = tid & 7;
        int lane = (tid >> 3) & 63;
        int nt   = (tid >> 9) & 15;
        int rest = tid >> 13;                // c*2 + kt
        int kt = rest & 1, c = rest >> 1;
        int kl = kt * 32 + ((lane >> 4) << 3) + j;   // k within chunk (0..63)
        int n  = nt * 16 + (lane & 15);
        int row;
        if (c < NSP) row = 13 + c * 64 + kl;
        else         row = (kl < NDN) ? kl : -1;
        pW1[tid] = (row >= 0) ? f2h(W1[(long)row * HID1 + n]) : (unsigned short)0;
    } else {
        int tid = (bid - 1920) * 256 + threadIdx.x;  // 32768 total
        int j    = tid & 7;
        int lane = (tid >> 3) & 63;
        int nt   = (tid >> 9) & 7;
        int kc   = tid >> 12;
        int k = kc * 32 + ((lane >> 4) << 3) + j;
        int n = nt * 16 + (lane & 15);
        pW2[tid] = f2h(W2[(long)k * HID2 + n]);
    }
}

// ---------------------------------------------------------------------------
// K1: logit0[b] = relu(X[b,:] @ lin_W + lin_b)
// ---------------------------------------------------------------------------
__global__ void k_lin(const float* __restrict__ X, const float* __restrict__ lw,
                      const float* __restrict__ lb, float* __restrict__ logit0) {
    int b = blockIdx.x * 256 + threadIdx.x;
    float s = lb[0];
    const float* xr = X + (long)b * XW;
#pragma unroll
    for (int i = 0; i < XW; i++) s = fmaf(xr[i], lw[i], s);
    logit0[b] = fmaxf(s, 0.f);
}

// ---------------------------------------------------------------------------
// K2: fused 3-layer AutoInt, MFMA fp16, register-resident chain.
// (unchanged from round 9: 4 independent samples/block, cat() chaining,
// in-register softmax; __launch_bounds__(256,4) -> VGPR 60, no spill.)
// ---------------------------------------------------------------------------
__global__ __launch_bounds__(256, 4) void k_interact(
    const int* __restrict__ sidx, const float* __restrict__ emb,
    const unsigned short* __restrict__ pW, const float* __restrict__ outW,
    float* __restrict__ p1)
{
    __shared__ __align__(16) unsigned short att_s[4][32 * 72];   // 18432 B

    const int wid  = threadIdx.x >> 6;
    const int lane = threadIdx.x & 63;
    const int b    = blockIdx.x * 4 + wid;
    unsigned short* att = att_s[wid];

    const int quad = lane >> 4;
    const int c16  = lane & 15;
    const float4v zero4 = {0.f, 0.f, 0.f, 0.f};

    // gather embeddings -> att (fp16), coalesced over lane=e
#pragma unroll
    for (int f = 0; f < NSP; f++) {
        int idx = sidx[b * NSP + f];
        att[f * 72 + lane] = f2h(emb[((long)(f * VOC + idx)) * EDIM + lane]);
    }
#pragma unroll
    for (int r = NSP; r < 32; r++) att[r * 72 + lane] = 0;   // zero pad rows
    __threadfence_block();

    for (int l = 0; l < NLAY; l++) {
        half8 Fatt[2][2];
#pragma unroll
        for (int qt = 0; qt < 2; qt++)
#pragma unroll
            for (int kt = 0; kt < 2; kt++)
                Fatt[qt][kt] = *(const half8*)&att[(qt*16 + c16)*72 + kt*32 + quad*8];

        const unsigned short* wl = pW + l * 16384;
        uint2 qpk[4][2];   // Q^T tiles [dt][qt]   (lane=q,   regs=d)
        uint2 kpk[4][2];   // K^T tiles [dt][keyt] (lane=key, regs=d)
        uint2 vpk[2][4];   // V   tiles [keyt][dt] (lane=d,   regs=key)
        uint2 rpk[4][2];   // R^T tiles [dt][qt]   (lane=q,   regs=d)

        // ---- projections: m = 0:Q^T 1:K^T 2:V 3:R^T ----
#pragma unroll
        for (int m = 0; m < 4; m++) {
            half8 Wf[4][2];
#pragma unroll
            for (int nt = 0; nt < 4; nt++)
#pragma unroll
                for (int kt = 0; kt < 2; kt++)
                    Wf[nt][kt] = *(const half8*)&wl[(m*8 + nt*2 + kt)*512 + lane*8];

            if (m == 2) {
#pragma unroll
                for (int qt = 0; qt < 2; qt++)
#pragma unroll
                    for (int dt = 0; dt < 4; dt++) {
                        float4v acc = __builtin_amdgcn_mfma_f32_16x16x32_f16(
                            Fatt[qt][0], Wf[dt][0], zero4, 0, 0, 0);
                        acc = __builtin_amdgcn_mfma_f32_16x16x32_f16(
                            Fatt[qt][1], Wf[dt][1], acc, 0, 0, 0);
                        vpk[qt][dt] = pkC(acc);
                    }
            } else {
#pragma unroll
                for (int dt = 0; dt < 4; dt++)
#pragma unroll
                    for (int qt = 0; qt < 2; qt++) {
                        float4v acc = __builtin_amdgcn_mfma_f32_16x16x32_f16(
                            Wf[dt][0], Fatt[qt][0], zero4, 0, 0, 0);
                        acc = __builtin_amdgcn_mfma_f32_16x16x32_f16(
                            Wf[dt][1], Fatt[qt][1], acc, 0, 0, 0);
                        if (m == 0)      qpk[dt][qt] = pkC(acc);
                        else if (m == 1) kpk[dt][qt] = pkC(acc);
                        else             rpk[dt][qt] = pkC(acc);
                    }
            }
        }

        // ---- S^T = K.Q^T, in-register softmax, pack P ----
        uint2 Ppk[2][2][2];     // [h][keyt][nq]  (lane=q, regs=key)
#pragma unroll
        for (int h = 0; h < 2; h++)
#pragma unroll
            for (int nq = 0; nq < 2; nq++) {
                half8 Qc = cat(qpk[h*2][nq], qpk[h*2+1][nq]);
                float4v S0 = __builtin_amdgcn_mfma_f32_16x16x32_f16(
                    cat(kpk[h*2][0], kpk[h*2+1][0]), Qc, zero4, 0, 0, 0);
                float4v S1 = __builtin_amdgcn_mfma_f32_16x16x32_f16(
                    cat(kpk[h*2][1], kpk[h*2+1][1]), Qc, zero4, 0, 0, 0);
                float sv[8];
#pragma unroll
                for (int r = 0; r < 4; r++) {
                    sv[r]     = S0[r];
                    sv[4 + r] = (quad*4 + r >= 10) ? -1e30f : S1[r];  // keys>=26
                }
                float mx = sv[0];
#pragma unroll
                for (int j = 1; j < 8; j++) mx = fmaxf(mx, sv[j]);
                mx = fmaxf(mx, __shfl_xor(mx, 16));
                mx = fmaxf(mx, __shfl_xor(mx, 32));
                float e[8], sum = 0.f;
#pragma unroll
                for (int j = 0; j < 8; j++) {
                    e[j] = (j >= 4 && quad*4 + (j-4) >= 10) ? 0.f : __expf(sv[j] - mx);
                    sum += e[j];
                }
                sum += __shfl_xor(sum, 16);
                sum += __shfl_xor(sum, 32);
                float inv = 1.f / sum;
                Ppk[h][0][nq].x = pkh(e[0]*inv, e[1]*inv);
                Ppk[h][0][nq].y = pkh(e[2]*inv, e[3]*inv);
                Ppk[h][1][nq].x = pkh(e[4]*inv, e[5]*inv);
                Ppk[h][1][nq].y = pkh(e[6]*inv, e[7]*inv);
            }

        // ---- O^T = V^T.P^T + R^T, relu, -> att ----
#pragma unroll
        for (int h = 0; h < 2; h++)
#pragma unroll
            for (int md = 0; md < 2; md++) {
                int dt = h*2 + md;
                half8 Vc = cat(vpk[0][dt], vpk[1][dt]);
#pragma unroll
                for (int nq = 0; nq < 2; nq++) {
                    float4v O = __builtin_amdgcn_mfma_f32_16x16x32_f16(
                        Vc, cat(Ppk[h][0][nq], Ppk[h][1][nq]), zero4, 0, 0, 0);
                    uint2 rp = rpk[dt][nq];
                    float4v o;
                    o[0] = fmaxf(O[0] + h2f((unsigned short)(rp.x & 0xFFFF)), 0.f);
                    o[1] = fmaxf(O[1] + h2f((unsigned short)(rp.x >> 16)),   0.f);
                    o[2] = fmaxf(O[2] + h2f((unsigned short)(rp.y & 0xFFFF)), 0.f);
                    o[3] = fmaxf(O[3] + h2f((unsigned short)(rp.y >> 16)),   0.f);
                    st4(&att[(nq*16 + c16)*72 + dt*16 + quad*4], o);
                }
            }
        __threadfence_block();
    }

    // ---- p1[b] = att_flat @ out_W[0:1664] (rows <26 only) ----
    float s = 0.f;
#pragma unroll
    for (int f = 0; f < NSP; f++)
        s = fmaf(h2f(att[f*72 + lane]), outW[f*EDIM + lane], s);
#pragma unroll
    for (int off = 32; off > 0; off >>= 1) s += __shfl_down(s, off);
    if (lane == 0) p1[b] = s;
}

// ---------------------------------------------------------------------------
// K3: fused DNN, MFMA fp16, ZERO-barrier K-loop.  M-tile = 32 samples,
// 1024 blocks (4/CU).  A-fragments load DIRECTLY from the fp32 emb table:
// frag rows are 32B-aligned slices of emb rows (2x float4 + 4 pkh) — no LDS
// staging, no per-chunk __syncthreads (round 9 had 54).  Dense cols = masked
// tail chunk (bounds-checked; pW1 zero-cols make masked lanes contribute 0).
// Barriers: 2 total (h1 exchange, h2 publish).
// ---------------------------------------------------------------------------
__global__ __launch_bounds__(256, 4) void k_dnn(
    const float* __restrict__ X, const int* __restrict__ sidx,
    const float* __restrict__ emb, const unsigned short* __restrict__ pW1,
    const float* __restrict__ b1, const unsigned short* __restrict__ pW2,
    const float* __restrict__ b2, const float* __restrict__ outW,
    const float* __restrict__ logit0, const float* __restrict__ p1,
    float* __restrict__ out)
{
    __shared__ __align__(16) unsigned short h1buf[32 * 264];   // 16896 B
    __shared__ __align__(16) unsigned short h2buf[32 * 136];   //  8704 B

    const int t    = threadIdx.x;
    const int lane = t & 63;
    const int w    = t >> 6;
    const int quad = lane >> 4;
    const int c16  = lane & 15;
    const int bM   = blockIdx.x * 32;

    float4v acc[2][4];
#pragma unroll
    for (int mt = 0; mt < 2; mt++)
#pragma unroll
        for (int nt = 0; nt < 4; nt++) acc[mt][nt] = (float4v){0.f, 0.f, 0.f, 0.f};

    // ---- GEMM1 over 26 emb feature-chunks (K=64 each), no barriers ----
    for (int c = 0; c < NSP; c++) {
        const float* r0 = emb + ((long)(c * VOC + sidx[(bM + c16) * NSP + c])) * EDIM;
        const float* r1 = emb + ((long)(c * VOC + sidx[(bM + 16 + c16) * NSP + c])) * EDIM;
#pragma unroll
        for (int kt = 0; kt < 2; kt++) {
            const int ko = kt * 32 + quad * 8;
            float4 a0 = *(const float4*)(r0 + ko), a1 = *(const float4*)(r0 + ko + 4);
            float4 b0 = *(const float4*)(r1 + ko), b1v = *(const float4*)(r1 + ko + 4);
            half8 Af[2];
            Af[0] = h8((uint4){ pkh(a0.x,a0.y), pkh(a0.z,a0.w), pkh(a1.x,a1.y), pkh(a1.z,a1.w) });
            Af[1] = h8((uint4){ pkh(b0.x,b0.y), pkh(b0.z,b0.w), pkh(b1v.x,b1v.y), pkh(b1v.z,b1v.w) });
            half8 Bf[4];
#pragma unroll
            for (int nt = 0; nt < 4; nt++)
                Bf[nt] = *(const half8*)&pW1[((long)((c*2 + kt)*16 + w*4 + nt) * 64 + lane) * 8];
#pragma unroll
            for (int mt = 0; mt < 2; mt++)
#pragma unroll
                for (int nt = 0; nt < 4; nt++)
                    acc[mt][nt] = __builtin_amdgcn_mfma_f32_16x16x32_f16(
                        Af[mt], Bf[nt], acc[mt][nt], 0, 0, 0);
        }
    }
    // ---- dense tail chunk (c=26, kt=0 only; kt=1 is all-zero in pW1) ----
    {
        half8 Af[2];
#pragma unroll
        for (int mt = 0; mt < 2; mt++) {
            const long xr = (long)(bM + mt*16 + c16) * XW + NSP;
            float v[8];
#pragma unroll
            for (int j = 0; j < 8; j++) {
                int k = quad * 8 + j;
                v[j] = (k < NDN) ? X[xr + k] : 0.f;   // masked: no OOB reads
            }
            Af[mt] = h8((uint4){ pkh(v[0],v[1]), pkh(v[2],v[3]),
                                 pkh(v[4],v[5]), pkh(v[6],v[7]) });
        }
        half8 Bf[4];
#pragma unroll
        for (int nt = 0; nt < 4; nt++)
            Bf[nt] = *(const half8*)&pW1[((long)((NSP*2)*16 + w*4 + nt) * 64 + lane) * 8];
#pragma unroll
        for (int mt = 0; mt < 2; mt++)
#pragma unroll
            for (int nt = 0; nt < 4; nt++)
                acc[mt][nt] = __builtin_amdgcn_mfma_f32_16x16x32_f16(
                    Af[mt], Bf[nt], acc[mt][nt], 0, 0, 0);
    }

    // ---- h1 = relu(acc + b1) -> LDS fp16 ----
#pragma unroll
    for (int nt = 0; nt < 4; nt++) {
        int n = w * 64 + nt * 16 + c16;
        float bias = b1[n];
#pragma unroll
        for (int mt = 0; mt < 2; mt++)
#pragma unroll
            for (int reg = 0; reg < 4; reg++)
                h1buf[(mt * 16 + quad * 4 + reg) * 264 + n] =
                    f2h(fmaxf(acc[mt][nt][reg] + bias, 0.f));
    }
    __syncthreads();

    // ---- GEMM2: h2 = relu(h1 @ W2 + b2), wave w -> cols [w*32, w*32+32) ----
    float4v acc2[2][2];
#pragma unroll
    for (int mt = 0; mt < 2; mt++)
#pragma unroll
        for (int n2 = 0; n2 < 2; n2++) acc2[mt][n2] = (float4v){0.f, 0.f, 0.f, 0.f};
#pragma unroll
    for (int kc2 = 0; kc2 < 8; kc2++) {
        half8 Bf2[2], Af2[2];
#pragma unroll
        for (int n2 = 0; n2 < 2; n2++)
            Bf2[n2] = *(const half8*)&pW2[((kc2 * 8 + w * 2 + n2) * 64 + lane) * 8];
#pragma unroll
        for (int mt = 0; mt < 2; mt++)
            Af2[mt] = *(const half8*)&h1buf[(mt * 16 + c16) * 264 + kc2 * 32 + quad * 8];
#pragma unroll
        for (int mt = 0; mt < 2; mt++)
#pragma unroll
            for (int n2 = 0; n2 < 2; n2++)
                acc2[mt][n2] = __builtin_amdgcn_mfma_f32_16x16x32_f16(
                    Af2[mt], Bf2[n2], acc2[mt][n2], 0, 0, 0);
    }

#pragma unroll
    for (int n2 = 0; n2 < 2; n2++) {
        int n = w * 32 + n2 * 16 + c16;
        float bias = b2[n];
#pragma unroll
        for (int mt = 0; mt < 2; mt++)
#pragma unroll
            for (int reg = 0; reg < 4; reg++)
                h2buf[(mt * 16 + quad * 4 + reg) * 136 + n] =
                    f2h(fmaxf(acc2[mt][n2][reg] + bias, 0.f));
    }
    __syncthreads();

    // ---- p2 + final sigmoid ----
    if (t < 32) {
        const float* ow2 = outW + NSP * EDIM;
        float s = 0.f;
#pragma unroll
        for (int c8 = 0; c8 < 16; c8++) {
            half8 h = *(const half8*)&h2buf[t * 136 + c8 * 8];
#pragma unroll
            for (int j = 0; j < 8; j++)
                s = fmaf((float)h[j], ow2[c8 * 8 + j], s);
        }
        int bb = bM + t;
        float logit = logit0[bb] + p1[bb] + s;
        out[bb] = 1.f / (1.f + __expf(-logit));
    }
}

// ---------------------------------------------------------------------------
extern "C" void kernel_launch(void* const* d_in, const int* in_sizes, int n_in,
                              void* d_out, int out_size, void* d_ws, size_t ws_size,
                              hipStream_t stream) {
    const float* X    = (const float*)d_in[0];
    const int*   sidx = (const int*)d_in[1];
    const float* emb  = (const float*)d_in[2];
    const float* Wq   = (const float*)d_in[3];
    const float* Wk   = (const float*)d_in[4];
    const float* Wv   = (const float*)d_in[5];
    const float* Wres = (const float*)d_in[6];
    const float* W1   = (const float*)d_in[7];
    const float* b1   = (const float*)d_in[8];
    const float* W2   = (const float*)d_in[9];
    const float* b2   = (const float*)d_in[10];
    const float* outW = (const float*)d_in[11];
    const float* linW = (const float*)d_in[12];
    const float* linb = (const float*)d_in[13];
    float* out = (float*)d_out;

    float* logit0 = (float*)d_ws;                          // 32768 f
    float* p1     = logit0 + BATCH;                        // 32768 f
    unsigned short* pW  = (unsigned short*)(p1 + BATCH);   // 49152 fp16
    unsigned short* pW1 = pW + 49152;                      // 442368 fp16
    unsigned short* pW2 = pW1 + 442368;                    // 32768 fp16

    k_pack<<<2048, 256, 0, stream>>>(Wq, Wk, Wv, Wres, W1, W2, pW, pW1, pW2);
    k_lin<<<BATCH / 256, 256, 0, stream>>>(X, linW, linb, logit0);
    k_interact<<<BATCH / 4, 256, 0, stream>>>(sidx, emb, pW, outW, p1);
    k_dnn<<<BATCH / 32, 256, 0, stream>>>(X, sidx, emb, pW1, b1, pW2, b2, outW,
                                          logit0, p1, out);
}

// Round 11
// 327.935 us; speedup vs baseline: 1.2372x; 1.2372x over previous
//
#include <hip/hip_runtime.h>
#include <math.h>

#define BATCH 32768
#define NSP 26
#define NDN 13
#define VOC 10000
#define EDIM 64
#define NLAY 3
#define HID1 256
#define HID2 128
#define XW 39             // NSP + NDN
#define KCH 27            // GEMM1 feature-chunks of 64: 26 emb features + 1 dense

typedef __fp16   fp16x2 __attribute__((ext_vector_type(2)));
typedef _Float16 half8  __attribute__((ext_vector_type(8)));
typedef float float4v   __attribute__((ext_vector_type(4)));

// ---- fp16 converts: all single-instruction on gfx950 ----
__device__ __forceinline__ unsigned pkh(float lo, float hi) {   // v_cvt_pkrtz_f16_f32
    fp16x2 h = __builtin_amdgcn_cvt_pkrtz(lo, hi);
    return __builtin_bit_cast(unsigned, h);
}
__device__ __forceinline__ unsigned short f2h(float f) {        // v_cvt_f16_f32 (RNE)
    return __builtin_bit_cast(unsigned short, (_Float16)f);
}
__device__ __forceinline__ float h2f(unsigned short h) {        // v_cvt_f32_f16
    return (float)__builtin_bit_cast(_Float16, h);
}
// pack a C-tile (4 f32 regs = rows quad*4+0..3, col c16) into 2 u32 fp16
__device__ __forceinline__ uint2 pkC(float4v c) {
    uint2 r; r.x = pkh(c[0], c[1]); r.y = pkh(c[2], c[3]); return r;
}
__device__ __forceinline__ void st4(unsigned short* p, float4v v) {
    *(uint2*)p = pkC(v);
}
// concat two packed C-tiles into one K=32 MFMA operand.  EXACT k-permutation
// trick: slots j=0..3 carry tile a (k=quad*4+j), slots 4..7 tile b
// (k=16+quad*4+(j-4)); same slot->k map for BOTH operands => dot unchanged.
__device__ __forceinline__ half8 cat(uint2 a, uint2 b) {
    union { unsigned u[4]; half8 h; } r;
    r.u[0] = a.x; r.u[1] = a.y; r.u[2] = b.x; r.u[3] = b.y;
    return r.h;
}
__device__ __forceinline__ half8 h8(uint4 u) {
    union { uint4 u; half8 h; } r; r.u = u; return r.h;
}

// ---------------------------------------------------------------------------
// K0: pack all weights into MFMA fragment order (fp16).
//  bid <  192 : Wq/Wk/Wv/Wres -> pW  [l][m][nt4][kt2][lane][j8]
//  192..1919  : W1 -> pW1 [c27][kt2][nt16][lane][j8], feature-chunk row order:
//               chunk c<26 covers W1 rows 13+c*64.. (emb feature c); chunk 26:
//               rows 0..12 (dense) then zero pad
//  1920..2047 : W2 -> pW2 [kc8][nt8][lane][j8]
// ---------------------------------------------------------------------------
__global__ void k_pack(const float* __restrict__ Wq, const float* __restrict__ Wk,
                       const float* __restrict__ Wv, const float* __restrict__ Wr,
                       const float* __restrict__ W1, const float* __restrict__ W2,
                       unsigned short* __restrict__ pW,
                       unsigned short* __restrict__ pW1,
                       unsigned short* __restrict__ pW2) {
    int bid = blockIdx.x;
    if (bid < 192) {
        int tid = bid * 256 + threadIdx.x;   // 49152 total
        int j    = tid & 7;
        int lane = (tid >> 3) & 63;
        int kt   = (tid >> 9) & 1;
        int nt   = (tid >> 10) & 3;
        int m    = (tid >> 12) & 3;
        int l    = tid >> 14;
        const float* W = (m == 0) ? Wq : (m == 1) ? Wk : (m == 2) ? Wv : Wr;
        int k = kt * 32 + ((lane >> 4) << 3) + j;
        int n = nt * 16 + (lane & 15);
        pW[tid] = f2h(W[l * EDIM * EDIM + k * EDIM + n]);
    } else if (bid < 1920) {
        int tid = (bid - 192) * 256 + threadIdx.x;   // 442368 total
        int j    = tid & 7;
        int lane = (tid >> 3) & 63;
        int nt   = (tid >> 9) & 15;
        int rest = tid >> 13;                // c*2 + kt
        int kt = rest & 1, c = rest >> 1;
        int kl = kt * 32 + ((lane >> 4) << 3) + j;   // k within chunk (0..63)
        int n  = nt * 16 + (lane & 15);
        int row;
        if (c < NSP) row = 13 + c * 64 + kl;
        else         row = (kl < NDN) ? kl : -1;
        pW1[tid] = (row >= 0) ? f2h(W1[(long)row * HID1 + n]) : (unsigned short)0;
    } else {
        int tid = (bid - 1920) * 256 + threadIdx.x;  // 32768 total
        int j    = tid & 7;
        int lane = (tid >> 3) & 63;
        int nt   = (tid >> 9) & 7;
        int kc   = tid >> 12;
        int k = kc * 32 + ((lane >> 4) << 3) + j;
        int n = nt * 16 + (lane & 15);
        pW2[tid] = f2h(W2[(long)k * HID2 + n]);
    }
}

// ---------------------------------------------------------------------------
// K1: logit0[b] = relu(X[b,:] @ lin_W + lin_b)
// ---------------------------------------------------------------------------
__global__ void k_lin(const float* __restrict__ X, const float* __restrict__ lw,
                      const float* __restrict__ lb, float* __restrict__ logit0) {
    int b = blockIdx.x * 256 + threadIdx.x;
    float s = lb[0];
    const float* xr = X + (long)b * XW;
#pragma unroll
    for (int i = 0; i < XW; i++) s = fmaf(xr[i], lw[i], s);
    logit0[b] = fmaxf(s, 0.f);
}

// ---------------------------------------------------------------------------
// K2: fused 3-layer AutoInt, MFMA fp16, register-resident chain.
// (unchanged from round 9: 4 independent samples/block, cat() chaining,
// in-register softmax; __launch_bounds__(256,4) -> VGPR 60, no spill.)
// ---------------------------------------------------------------------------
__global__ __launch_bounds__(256, 4) void k_interact(
    const int* __restrict__ sidx, const float* __restrict__ emb,
    const unsigned short* __restrict__ pW, const float* __restrict__ outW,
    float* __restrict__ p1)
{
    __shared__ __align__(16) unsigned short att_s[4][32 * 72];   // 18432 B

    const int wid  = threadIdx.x >> 6;
    const int lane = threadIdx.x & 63;
    const int b    = blockIdx.x * 4 + wid;
    unsigned short* att = att_s[wid];

    const int quad = lane >> 4;
    const int c16  = lane & 15;
    const float4v zero4 = {0.f, 0.f, 0.f, 0.f};

    // gather embeddings -> att (fp16), coalesced over lane=e
#pragma unroll
    for (int f = 0; f < NSP; f++) {
        int idx = sidx[b * NSP + f];
        att[f * 72 + lane] = f2h(emb[((long)(f * VOC + idx)) * EDIM + lane]);
    }
#pragma unroll
    for (int r = NSP; r < 32; r++) att[r * 72 + lane] = 0;   // zero pad rows
    __threadfence_block();

    for (int l = 0; l < NLAY; l++) {
        half8 Fatt[2][2];
#pragma unroll
        for (int qt = 0; qt < 2; qt++)
#pragma unroll
            for (int kt = 0; kt < 2; kt++)
                Fatt[qt][kt] = *(const half8*)&att[(qt*16 + c16)*72 + kt*32 + quad*8];

        const unsigned short* wl = pW + l * 16384;
        uint2 qpk[4][2];   // Q^T tiles [dt][qt]   (lane=q,   regs=d)
        uint2 kpk[4][2];   // K^T tiles [dt][keyt] (lane=key, regs=d)
        uint2 vpk[2][4];   // V   tiles [keyt][dt] (lane=d,   regs=key)
        uint2 rpk[4][2];   // R^T tiles [dt][qt]   (lane=q,   regs=d)

        // ---- projections: m = 0:Q^T 1:K^T 2:V 3:R^T ----
#pragma unroll
        for (int m = 0; m < 4; m++) {
            half8 Wf[4][2];
#pragma unroll
            for (int nt = 0; nt < 4; nt++)
#pragma unroll
                for (int kt = 0; kt < 2; kt++)
                    Wf[nt][kt] = *(const half8*)&wl[(m*8 + nt*2 + kt)*512 + lane*8];

            if (m == 2) {
#pragma unroll
                for (int qt = 0; qt < 2; qt++)
#pragma unroll
                    for (int dt = 0; dt < 4; dt++) {
                        float4v acc = __builtin_amdgcn_mfma_f32_16x16x32_f16(
                            Fatt[qt][0], Wf[dt][0], zero4, 0, 0, 0);
                        acc = __builtin_amdgcn_mfma_f32_16x16x32_f16(
                            Fatt[qt][1], Wf[dt][1], acc, 0, 0, 0);
                        vpk[qt][dt] = pkC(acc);
                    }
            } else {
#pragma unroll
                for (int dt = 0; dt < 4; dt++)
#pragma unroll
                    for (int qt = 0; qt < 2; qt++) {
                        float4v acc = __builtin_amdgcn_mfma_f32_16x16x32_f16(
                            Wf[dt][0], Fatt[qt][0], zero4, 0, 0, 0);
                        acc = __builtin_amdgcn_mfma_f32_16x16x32_f16(
                            Wf[dt][1], Fatt[qt][1], acc, 0, 0, 0);
                        if (m == 0)      qpk[dt][qt] = pkC(acc);
                        else if (m == 1) kpk[dt][qt] = pkC(acc);
                        else             rpk[dt][qt] = pkC(acc);
                    }
            }
        }

        // ---- S^T = K.Q^T, in-register softmax, pack P ----
        uint2 Ppk[2][2][2];     // [h][keyt][nq]  (lane=q, regs=key)
#pragma unroll
        for (int h = 0; h < 2; h++)
#pragma unroll
            for (int nq = 0; nq < 2; nq++) {
                half8 Qc = cat(qpk[h*2][nq], qpk[h*2+1][nq]);
                float4v S0 = __builtin_amdgcn_mfma_f32_16x16x32_f16(
                    cat(kpk[h*2][0], kpk[h*2+1][0]), Qc, zero4, 0, 0, 0);
                float4v S1 = __builtin_amdgcn_mfma_f32_16x16x32_f16(
                    cat(kpk[h*2][1], kpk[h*2+1][1]), Qc, zero4, 0, 0, 0);
                float sv[8];
#pragma unroll
                for (int r = 0; r < 4; r++) {
                    sv[r]     = S0[r];
                    sv[4 + r] = (quad*4 + r >= 10) ? -1e30f : S1[r];  // keys>=26
                }
                float mx = sv[0];
#pragma unroll
                for (int j = 1; j < 8; j++) mx = fmaxf(mx, sv[j]);
                mx = fmaxf(mx, __shfl_xor(mx, 16));
                mx = fmaxf(mx, __shfl_xor(mx, 32));
                float e[8], sum = 0.f;
#pragma unroll
                for (int j = 0; j < 8; j++) {
                    e[j] = (j >= 4 && quad*4 + (j-4) >= 10) ? 0.f : __expf(sv[j] - mx);
                    sum += e[j];
                }
                sum += __shfl_xor(sum, 16);
                sum += __shfl_xor(sum, 32);
                float inv = 1.f / sum;
                Ppk[h][0][nq].x = pkh(e[0]*inv, e[1]*inv);
                Ppk[h][0][nq].y = pkh(e[2]*inv, e[3]*inv);
                Ppk[h][1][nq].x = pkh(e[4]*inv, e[5]*inv);
                Ppk[h][1][nq].y = pkh(e[6]*inv, e[7]*inv);
            }

        // ---- O^T = V^T.P^T + R^T, relu, -> att ----
#pragma unroll
        for (int h = 0; h < 2; h++)
#pragma unroll
            for (int md = 0; md < 2; md++) {
                int dt = h*2 + md;
                half8 Vc = cat(vpk[0][dt], vpk[1][dt]);
#pragma unroll
                for (int nq = 0; nq < 2; nq++) {
                    float4v O = __builtin_amdgcn_mfma_f32_16x16x32_f16(
                        Vc, cat(Ppk[h][0][nq], Ppk[h][1][nq]), zero4, 0, 0, 0);
                    uint2 rp = rpk[dt][nq];
                    float4v o;
                    o[0] = fmaxf(O[0] + h2f((unsigned short)(rp.x & 0xFFFF)), 0.f);
                    o[1] = fmaxf(O[1] + h2f((unsigned short)(rp.x >> 16)),   0.f);
                    o[2] = fmaxf(O[2] + h2f((unsigned short)(rp.y & 0xFFFF)), 0.f);
                    o[3] = fmaxf(O[3] + h2f((unsigned short)(rp.y >> 16)),   0.f);
                    st4(&att[(nq*16 + c16)*72 + dt*16 + quad*4], o);
                }
            }
        __threadfence_block();
    }

    // ---- p1[b] = att_flat @ out_W[0:1664] (rows <26 only) ----
    float s = 0.f;
#pragma unroll
    for (int f = 0; f < NSP; f++)
        s = fmaf(h2f(att[f*72 + lane]), outW[f*EDIM + lane], s);
#pragma unroll
    for (int off = 32; off > 0; off >>= 1) s += __shfl_down(s, off);
    if (lane == 0) p1[b] = s;
}

// ---------------------------------------------------------------------------
// K3: fused DNN, MFMA fp16.  Round-9 staged structure + two fixes:
//  (1) M-tile 32 -> grid 1024 = 4 blocks/CU (round 9 was grid-limited at 2);
//  (2) double-buffered Abuf -> ONE barrier per K-chunk (29 total vs 54);
//      stage(c+1) global loads overlap MFMA(c).
// Staging stays fully coalesced: 8 threads/row x 2 float4 (256B emb rows).
// LDS 34816 B.  Round 10's barrier-free scatter-gather variant regressed
// (latency-chained 16B gathers, doubled B traffic) — reverted.
// ---------------------------------------------------------------------------
__global__ __launch_bounds__(256, 4) void k_dnn(
    const float* __restrict__ X, const int* __restrict__ sidx,
    const float* __restrict__ emb, const unsigned short* __restrict__ pW1,
    const float* __restrict__ b1, const unsigned short* __restrict__ pW2,
    const float* __restrict__ b2, const float* __restrict__ outW,
    const float* __restrict__ logit0, const float* __restrict__ p1,
    float* __restrict__ out)
{
    __shared__ __align__(16) unsigned short Abuf[2][32 * 72];  //  9216 B
    __shared__ __align__(16) unsigned short h1buf[32 * 264];   // 16896 B
    __shared__ __align__(16) unsigned short h2buf[32 * 136];   //  8704 B

    const int t    = threadIdx.x;
    const int lane = t & 63;
    const int w    = t >> 6;
    const int quad = lane >> 4;
    const int c16  = lane & 15;
    const int bM   = blockIdx.x * 32;
    const int sr   = t >> 3;      // staging sample (0..31)
    const int part = t & 7;       // staging 8-float slice (0..7)

    auto stage = [&](int c) {
        uint4 wv;
        if (c < NSP) {
            int idx = sidx[(bM + sr) * NSP + c];
            const float4* src = (const float4*)(emb + ((long)(c * VOC + idx)) * EDIM + part * 8);
            float4 a = src[0], b = src[1];
            wv = (uint4){ pkh(a.x, a.y), pkh(a.z, a.w), pkh(b.x, b.y), pkh(b.z, b.w) };
        } else {
            float v[8];
#pragma unroll
            for (int j = 0; j < 8; j++) {
                int k = part * 8 + j;
                v[j] = (k < NDN) ? X[(long)(bM + sr) * XW + NSP + k] : 0.f;
            }
            wv = (uint4){ pkh(v[0], v[1]), pkh(v[2], v[3]), pkh(v[4], v[5]), pkh(v[6], v[7]) };
        }
        *(uint4*)&Abuf[c & 1][sr * 72 + part * 8] = wv;
    };

    float4v acc[2][4];
#pragma unroll
    for (int mt = 0; mt < 2; mt++)
#pragma unroll
        for (int nt = 0; nt < 4; nt++) acc[mt][nt] = (float4v){0.f, 0.f, 0.f, 0.f};

    stage(0);
    __syncthreads();
    for (int c = 0; c < KCH; c++) {
        if (c + 1 < KCH) stage(c + 1);            // overlaps MFMA below
        const unsigned short* Ab = Abuf[c & 1];
#pragma unroll
        for (int kt = 0; kt < 2; kt++) {
            half8 Bf[4], Af[2];
#pragma unroll
            for (int nt = 0; nt < 4; nt++)
                Bf[nt] = *(const half8*)&pW1[((long)((c*2 + kt)*16 + w*4 + nt) * 64 + lane) * 8];
#pragma unroll
            for (int mt = 0; mt < 2; mt++)
                Af[mt] = *(const half8*)&Ab[(mt*16 + c16)*72 + kt*32 + quad*8];
#pragma unroll
            for (int mt = 0; mt < 2; mt++)
#pragma unroll
                for (int nt = 0; nt < 4; nt++)
                    acc[mt][nt] = __builtin_amdgcn_mfma_f32_16x16x32_f16(
                        Af[mt], Bf[nt], acc[mt][nt], 0, 0, 0);
        }
        __syncthreads();
    }

    // ---- h1 = relu(acc + b1) -> LDS fp16 ----
#pragma unroll
    for (int nt = 0; nt < 4; nt++) {
        int n = w * 64 + nt * 16 + c16;
        float bias = b1[n];
#pragma unroll
        for (int mt = 0; mt < 2; mt++)
#pragma unroll
            for (int reg = 0; reg < 4; reg++)
                h1buf[(mt * 16 + quad * 4 + reg) * 264 + n] =
                    f2h(fmaxf(acc[mt][nt][reg] + bias, 0.f));
    }
    __syncthreads();

    // ---- GEMM2: h2 = relu(h1 @ W2 + b2), wave w -> cols [w*32, w*32+32) ----
    float4v acc2[2][2];
#pragma unroll
    for (int mt = 0; mt < 2; mt++)
#pragma unroll
        for (int n2 = 0; n2 < 2; n2++) acc2[mt][n2] = (float4v){0.f, 0.f, 0.f, 0.f};
#pragma unroll
    for (int kc2 = 0; kc2 < 8; kc2++) {
        half8 Bf2[2], Af2[2];
#pragma unroll
        for (int n2 = 0; n2 < 2; n2++)
            Bf2[n2] = *(const half8*)&pW2[((kc2 * 8 + w * 2 + n2) * 64 + lane) * 8];
#pragma unroll
        for (int mt = 0; mt < 2; mt++)
            Af2[mt] = *(const half8*)&h1buf[(mt * 16 + c16) * 264 + kc2 * 32 + quad * 8];
#pragma unroll
        for (int mt = 0; mt < 2; mt++)
#pragma unroll
            for (int n2 = 0; n2 < 2; n2++)
                acc2[mt][n2] = __builtin_amdgcn_mfma_f32_16x16x32_f16(
                    Af2[mt], Bf2[n2], acc2[mt][n2], 0, 0, 0);
    }

#pragma unroll
    for (int n2 = 0; n2 < 2; n2++) {
        int n = w * 32 + n2 * 16 + c16;
        float bias = b2[n];
#pragma unroll
        for (int mt = 0; mt < 2; mt++)
#pragma unroll
            for (int reg = 0; reg < 4; reg++)
                h2buf[(mt * 16 + quad * 4 + reg) * 136 + n] =
                    f2h(fmaxf(acc2[mt][n2][reg] + bias, 0.f));
    }
    __syncthreads();

    // ---- p2 + final sigmoid ----
    if (t < 32) {
        const float* ow2 = outW + NSP * EDIM;
        float s = 0.f;
#pragma unroll
        for (int c8 = 0; c8 < 16; c8++) {
            half8 h = *(const half8*)&h2buf[t * 136 + c8 * 8];
#pragma unroll
            for (int j = 0; j < 8; j++)
                s = fmaf((float)h[j], ow2[c8 * 8 + j], s);
        }
        int bb = bM + t;
        float logit = logit0[bb] + p1[bb] + s;
        out[bb] = 1.f / (1.f + __expf(-logit));
    }
}

// ---------------------------------------------------------------------------
extern "C" void kernel_launch(void* const* d_in, const int* in_sizes, int n_in,
                              void* d_out, int out_size, void* d_ws, size_t ws_size,
                              hipStream_t stream) {
    const float* X    = (const float*)d_in[0];
    const int*   sidx = (const int*)d_in[1];
    const float* emb  = (const float*)d_in[2];
    const float* Wq   = (const float*)d_in[3];
    const float* Wk   = (const float*)d_in[4];
    const float* Wv   = (const float*)d_in[5];
    const float* Wres = (const float*)d_in[6];
    const float* W1   = (const float*)d_in[7];
    const float* b1   = (const float*)d_in[8];
    const float* W2   = (const float*)d_in[9];
    const float* b2   = (const float*)d_in[10];
    const float* outW = (const float*)d_in[11];
    const float* linW = (const float*)d_in[12];
    const float* linb = (const float*)d_in[13];
    float* out = (float*)d_out;

    float* logit0 = (float*)d_ws;                          // 32768 f
    float* p1     = logit0 + BATCH;                        // 32768 f
    unsigned short* pW  = (unsigned short*)(p1 + BATCH);   // 49152 fp16
    unsigned short* pW1 = pW + 49152;                      // 442368 fp16
    unsigned short* pW2 = pW1 + 442368;                    // 32768 fp16

    k_pack<<<2048, 256, 0, stream>>>(Wq, Wk, Wv, Wres, W1, W2, pW, pW1, pW2);
    k_lin<<<BATCH / 256, 256, 0, stream>>>(X, linW, linb, logit0);
    k_interact<<<BATCH / 4, 256, 0, stream>>>(sidx, emb, pW, outW, p1);
    k_dnn<<<BATCH / 32, 256, 0, stream>>>(X, sidx, emb, pW1, b1, pW2, b2, outW,
                                          logit0, p1, out);
}